// Round 1
// baseline (161.732 us; speedup 1.0000x reference)
//
#include <hip/hip_runtime.h>

// ForgetMult: h_t = f_t * x_t + (1 - f_t) * h_{t-1}, independent per (b, h).
// x, f: [B, T, H] fp32; hidden_init: [B, H] fp32; out: [B, T, H] fp32.
// One thread per (b, h) channel; serial loop over t with stride H (coalesced
// across the wave since consecutive lanes hold consecutive h).
//
// Recurrence rewritten as h = fma(1-f, h, f*x): the loop-carried chain is a
// single FMA (~4 cy); (1-f) and f*x are off the critical path. #pragma unroll
// 16 exposes 32 independent global loads per wave so the compiler can cluster
// them ahead of the FMA chain and keep ~8 KB/wave of HBM traffic in flight.

__global__ __launch_bounds__(128) void forget_mult_kernel(
    const float* __restrict__ x, const float* __restrict__ f,
    const float* __restrict__ h0, float* __restrict__ out,
    int T, int H) {
  const int tid = blockIdx.x * blockDim.x + threadIdx.x;  // in [0, B*H)
  const int b = tid / H;
  const int h = tid - b * H;
  int base = b * T * H + h;  // B*T*H = 67,108,864 < 2^31, int is safe

  float hv = h0[tid];

#pragma unroll 16
  for (int t = 0; t < T; ++t) {
    const float xv = x[base];
    const float fv = f[base];
    const float c = fv * xv;        // off-chain
    const float g = 1.0f - fv;      // off-chain
    hv = fmaf(g, hv, c);            // single-FMA loop-carried dependence
    out[base] = hv;
    base += H;
  }
}

extern "C" void kernel_launch(void* const* d_in, const int* in_sizes, int n_in,
                              void* d_out, int out_size, void* d_ws, size_t ws_size,
                              hipStream_t stream) {
  const float* x = (const float*)d_in[0];
  const float* f = (const float*)d_in[1];
  const float* h0 = (const float*)d_in[2];
  float* out = (float*)d_out;

  const int BH = in_sizes[2];            // B * H = 32768
  const int T = in_sizes[0] / BH;        // 2048
  const int H = 1024;                    // per setup_inputs(); B = BH / H

  const int block = 128;
  const int grid = (BH + block - 1) / block;  // 256 blocks -> 1 per CU
  forget_mult_kernel<<<grid, block, 0, stream>>>(x, f, h0, out, T, H);
}